// Round 3
// baseline (350.613 us; speedup 1.0000x reference)
//
#include <hip/hip_runtime.h>
#include <math.h>

#define T_DIM 4096
#define TRACE 64
#define CTX 64

typedef float vfloat4 __attribute__((ext_vector_type(4)));  // clang-native, OK for nontemporal builtins

// One block per t. Precompute per-t trig (64 ctx) + decay (64 trace) in LDS.
// k-invariant cos/sin/dec hoisted to registers; all 16 global float4 loads
// issued before any compute (MLP ~16/wave) to cover HBM latency.
__global__ __launch_bounds__(256) void ffm_kernel(
    const float* __restrict__ state_re,
    const float* __restrict__ state_im,
    const float* __restrict__ x_re,
    const float* __restrict__ x_im,
    const float* __restrict__ a,
    const float* __restrict__ b,
    const int*   __restrict__ ivec,
    const int*   __restrict__ jvec,
    float* __restrict__ out,       // [T, TRACE, CTX, 2] interleaved re/im
    float* __restrict__ out_cnt)   // [T] (j+i) stored as float values
{
    const int t   = blockIdx.x;
    const int tid = threadIdx.x;

    __shared__ float s_cos[CTX];
    __shared__ float s_sin[CTX];
    __shared__ float s_dec[TRACE];

    const float tf = (float)jvec[t];
    if (tid < CTX) {
        float s, c;
        sincosf(b[tid] * tf, &s, &c);   // accurate libm: only 64/block
        s_cos[tid] = c;
        s_sin[tid] = s;
    } else if (tid < CTX + TRACE) {
        const int tr = tid - CTX;
        s_dec[tr] = expf(-fabsf(a[tr]) * tf);
    }
    if (tid == 0) {
        out_cnt[t] = (float)(jvec[t] + ivec[t]);
    }
    __syncthreads();

    // k-invariant per-thread factors: c0 = ((tid + k*256)*4) & 63 == (tid*4)&63
    const int c0 = (tid * 4) & 63;
    const vfloat4 c4 = *(const vfloat4*)&s_cos[c0];
    const vfloat4 s4 = *(const vfloat4*)&s_sin[c0];
    const int tr0 = tid >> 4;          // tr for k: tr0 + k*16
    float dec[4];
    dec[0] = s_dec[tr0];
    dec[1] = s_dec[tr0 + 16];
    dec[2] = s_dec[tr0 + 32];
    dec[3] = s_dec[tr0 + 48];

    const size_t base = (size_t)t * (TRACE * CTX);
    const vfloat4* sre = (const vfloat4*)(state_re + base);
    const vfloat4* sim = (const vfloat4*)(state_im + base);
    const vfloat4* xre = (const vfloat4*)(x_re + base);
    const vfloat4* xim = (const vfloat4*)(x_im + base);
    vfloat4* o = (vfloat4*)(out + base * 2);

    // Phase 1: issue all 16 global loads (keeps ~16 vmem ops in flight).
    vfloat4 vre[4], vim[4], vxr[4], vxi[4];
    #pragma unroll
    for (int k = 0; k < 4; ++k) {
        const int g = tid + k * 256;
        vre[k] = sre[g];
        vim[k] = sim[g];
        vxr[k] = xre[g];
        vxi[k] = xim[g];
    }

    // Phase 2: compute + nontemporal store (output is never re-read).
    #pragma unroll
    for (int k = 0; k < 4; ++k) {
        const int g = tid + k * 256;
        const float d = dec[k];
        const float gr0 = d * c4.x, gi0 = d * s4.x;
        const float gr1 = d * c4.y, gi1 = d * s4.y;
        const float gr2 = d * c4.z, gi2 = d * s4.z;
        const float gr3 = d * c4.w, gi3 = d * s4.w;

        vfloat4 o0, o1;
        o0.x = fmaf(vre[k].x, gr0, fmaf(-vim[k].x, gi0, vxr[k].x));
        o0.y = fmaf(vre[k].x, gi0, fmaf( vim[k].x, gr0, vxi[k].x));
        o0.z = fmaf(vre[k].y, gr1, fmaf(-vim[k].y, gi1, vxr[k].y));
        o0.w = fmaf(vre[k].y, gi1, fmaf( vim[k].y, gr1, vxi[k].y));
        o1.x = fmaf(vre[k].z, gr2, fmaf(-vim[k].z, gi2, vxr[k].z));
        o1.y = fmaf(vre[k].z, gi2, fmaf( vim[k].z, gr2, vxi[k].z));
        o1.z = fmaf(vre[k].w, gr3, fmaf(-vim[k].w, gi3, vxr[k].w));
        o1.w = fmaf(vre[k].w, gi3, fmaf( vim[k].w, gr3, vxi[k].w));

        __builtin_nontemporal_store(o0, &o[2 * g + 0]);
        __builtin_nontemporal_store(o1, &o[2 * g + 1]);
    }
}

extern "C" void kernel_launch(void* const* d_in, const int* in_sizes, int n_in,
                              void* d_out, int out_size, void* d_ws, size_t ws_size,
                              hipStream_t stream) {
    const float* state_re = (const float*)d_in[0];
    const float* state_im = (const float*)d_in[1];
    const float* x_re     = (const float*)d_in[2];
    const float* x_im     = (const float*)d_in[3];
    const float* a        = (const float*)d_in[4];
    const float* b        = (const float*)d_in[5];
    const int*   iv       = (const int*)d_in[6];
    const int*   jv       = (const int*)d_in[7];

    float* out     = (float*)d_out;
    float* out_cnt = out + (size_t)T_DIM * TRACE * CTX * 2;

    ffm_kernel<<<T_DIM, 256, 0, stream>>>(state_re, state_im, x_re, x_im,
                                          a, b, iv, jv, out, out_cnt);
}